// Round 14
// baseline (185.565 us; speedup 1.0000x reference)
//
#include <hip/hip_runtime.h>

typedef _Float16 h8 __attribute__((ext_vector_type(8)));
typedef _Float16 h4 __attribute__((ext_vector_type(4)));
typedef float f4 __attribute__((ext_vector_type(4)));

constexpr int NB = 64;     // batch
constexpr int NI = 2048;   // input capsules
constexpr int NQ = 16;     // input dim
constexpr int NJ = 32;     // num capsules
constexpr int NP = 32;     // dim capsule
constexpr int NIP = NI / 2;         // 1024 i-pairs
constexpr int VSZ = NB * NJ * NP;   // 65536 per v-buffer

// ---------------------------------------------------------------------------
// MFMA plan (single-f16 W, i-PAIRED K):
//   per (j, ipair): D[p16,b16] += over K=32: k<16 -> W[j,i_e,p,q=k]*x[b,i_e,q]
//                                      k>=16 -> W[j,i_o,p,q=k-16]*x[b,i_o,q]
//   A lane layout: row p=l&15 (pf frag adds +16), i = l>=32 ? i_o : i_e
//   B lane layout: col b=(l&15)+16bf, same (i,q) lane split as A
//   D lane layout: col b=l&15, row p=(l>>4)*4+reg (+16 per pf)
// R14 = R11 base + ONE change: accum processes TWO j per block sharing the
// xp (B) stream in registers -> xp L2 traffic halves (256->128 MB/pass).
// wacc / logits / xpack / zero / squash byte-identical to R11 (136.5us).
// ---------------------------------------------------------------------------

__global__ __launch_bounds__(256)
void zero_kernel(f4* __restrict__ p)
{
    const f4 z = {0.f, 0.f, 0.f, 0.f};
    p[(size_t)blockIdx.x * 256 + threadIdx.x] = z;
}

// x pack, paired: xp[(ip*4+bf)*64 + l] = x[b=(l&15)+16bf, i=2ip+(l>=32), q0..q0+7]
__global__ __launch_bounds__(256)
void xpack_kernel(const float* __restrict__ X, h8* __restrict__ xp)
{
    const int ip = blockIdx.x;
    const int t = threadIdx.x;
    const int bf = t >> 6, l = t & 63;
    const int b = (l & 15) + 16 * bf;
    const int i = 2 * ip + (l >= 32 ? 1 : 0);
    const int q0 = ((l >> 4) & 1) * 8;
    const float* xs = X + ((size_t)b * NI + i) * NQ + q0;
    const float4 u = *reinterpret_cast<const float4*>(xs);
    const float4 v = *reinterpret_cast<const float4*>(xs + 4);
    h8 h;
    h[0] = (_Float16)u.x; h[1] = (_Float16)u.y; h[2] = (_Float16)u.z; h[3] = (_Float16)u.w;
    h[4] = (_Float16)v.x; h[5] = (_Float16)v.y; h[6] = (_Float16)v.z; h[7] = (_Float16)v.w;
    xp[(size_t)(ip * 4 + bf) * 64 + l] = h;
}

__device__ inline float sqscale(float s2)
{
    return s2 / ((1.f + s2) * sqrtf(s2 + 1e-7f));
}

// K0: fused W pack + pass-A uniform accumulation.  (R11 verbatim)
__global__ __launch_bounds__(512)
void wacc_kernel(const float* __restrict__ Wg, const h8* __restrict__ xp,
                 h8* __restrict__ wp, float* __restrict__ ACC)
{
    const int t = threadIdx.x, wv = t >> 6, l = t & 63;
    const int j = blockIdx.x >> 4, is = blockIdx.x & 15;
    const int ioff = (l >= 32) ? 1 : 0;
    const int q0 = ((l >> 4) & 1) * 8;
    const int pbase = is * 64 + wv * 8;

    f4 D[2][4];
#pragma unroll
    for (int pf = 0; pf < 2; ++pf)
#pragma unroll
        for (int bf = 0; bf < 4; ++bf) { f4 Z = {0.f, 0.f, 0.f, 0.f}; D[pf][bf] = Z; }

    const float* wgl = Wg + ((size_t)j * NI + ioff) * (NP * NQ) + (size_t)(l & 15) * NQ + q0;

    f4 u0, u1, v0, v1;
    {
        const float* s0 = wgl + (size_t)(2 * pbase) * (NP * NQ);
        u0 = *reinterpret_cast<const f4*>(s0);
        u1 = *reinterpret_cast<const f4*>(s0 + 4);
        v0 = *reinterpret_cast<const f4*>(s0 + 16 * NQ);
        v1 = *reinterpret_cast<const f4*>(s0 + 16 * NQ + 4);
    }
    h8 B0, B1, B2, B3;
    {
        const h8* xpb = xp + (size_t)pbase * 4 * 64 + l;
        B0 = xpb[0]; B1 = xpb[64]; B2 = xpb[128]; B3 = xpb[192];
    }

#pragma unroll 1
    for (int ipl = 0; ipl < 8; ++ipl) {
        const int ipg = pbase + ipl;
        const int nip = (ipl < 7) ? ipg + 1 : ipg;
        f4 nu0, nu1, nv0, nv1;
        {
            const float* s0 = wgl + (size_t)(2 * nip) * (NP * NQ);
            nu0 = *reinterpret_cast<const f4*>(s0);
            nu1 = *reinterpret_cast<const f4*>(s0 + 4);
            nv0 = *reinterpret_cast<const f4*>(s0 + 16 * NQ);
            nv1 = *reinterpret_cast<const f4*>(s0 + 16 * NQ + 4);
        }
        h8 nB0, nB1, nB2, nB3;
        {
            const h8* xpb = xp + (size_t)nip * 4 * 64 + l;
            nB0 = xpb[0]; nB1 = xpb[64]; nB2 = xpb[128]; nB3 = xpb[192];
        }

        h8 A0, A1;
#pragma unroll
        for (int e = 0; e < 4; ++e) {
            A0[e] = (_Float16)u0[e]; A0[e + 4] = (_Float16)u1[e];
            A1[e] = (_Float16)v0[e]; A1[e + 4] = (_Float16)v1[e];
        }
        const size_t wo = ((size_t)j * NIP + ipg) * 2 * 64 + l;
        wp[wo] = A0;
        wp[wo + 64] = A1;
        D[0][0] = __builtin_amdgcn_mfma_f32_16x16x32_f16(A0, B0, D[0][0], 0, 0, 0);
        D[1][0] = __builtin_amdgcn_mfma_f32_16x16x32_f16(A1, B0, D[1][0], 0, 0, 0);
        D[0][1] = __builtin_amdgcn_mfma_f32_16x16x32_f16(A0, B1, D[0][1], 0, 0, 0);
        D[1][1] = __builtin_amdgcn_mfma_f32_16x16x32_f16(A1, B1, D[1][1], 0, 0, 0);
        D[0][2] = __builtin_amdgcn_mfma_f32_16x16x32_f16(A0, B2, D[0][2], 0, 0, 0);
        D[1][2] = __builtin_amdgcn_mfma_f32_16x16x32_f16(A1, B2, D[1][2], 0, 0, 0);
        D[0][3] = __builtin_amdgcn_mfma_f32_16x16x32_f16(A0, B3, D[0][3], 0, 0, 0);
        D[1][3] = __builtin_amdgcn_mfma_f32_16x16x32_f16(A1, B3, D[1][3], 0, 0, 0);
        u0 = nu0; u1 = nu1; v0 = nv0; v1 = nv1;
        B0 = nB0; B1 = nB1; B2 = nB2; B3 = nB3;
    }

    __shared__ float R[8][64 * 36];
#pragma unroll
    for (int pf = 0; pf < 2; ++pf)
#pragma unroll
        for (int bf = 0; bf < 4; ++bf) {
            const int b = (l & 15) + 16 * bf, p = (l >> 4) * 4 + 16 * pf;
            *reinterpret_cast<f4*>(&R[wv][b * 36 + p]) = D[pf][bf];
        }
    __syncthreads();
#pragma unroll
    for (int k = 0; k < 4; ++k) {
        const int id = t + k * 512;
        const int b = id >> 5, p = id & 31;
        float s = 0.f;
#pragma unroll
        for (int w8 = 0; w8 < 8; ++w8) s += R[w8][b * 36 + p];
        atomicAdd(ACC + ((size_t)b * NJ + j) * NP + p, s);
    }
}

// K1: logits + softmax -> c (f16). S pre-squashed.  (R11 verbatim)
__global__ __launch_bounds__(512)
void logits_kernel(const h8* __restrict__ wp, const h8* __restrict__ xp,
                   const float* __restrict__ S, _Float16* __restrict__ cp)
{
    __shared__ float L[8][32][64];
    const int t = threadIdx.x, wv = t >> 6, l = t & 63;
    const int i0 = blockIdx.x * 8;
    const int ip0 = blockIdx.x * 4;
    const bool lo = l >= 32;
    h8 zh;
#pragma unroll
    for (int e = 0; e < 8; ++e) zh[e] = (_Float16)0.f;

#pragma unroll 1
    for (int jj = 0; jj < 4; ++jj) {
        const int j = wv * 4 + jj;

        float sreg[4][8];
#pragma unroll
        for (int bf = 0; bf < 4; ++bf) {
            const int b = (l & 15) + 16 * bf;
            const size_t base = ((size_t)b * NJ + j) * NP + (l >> 4) * 4;
            const f4 s0 = *reinterpret_cast<const f4*>(S + base);
            const f4 s1 = *reinterpret_cast<const f4*>(S + base + 16);
#pragma unroll
            for (int r = 0; r < 4; ++r) { sreg[bf][r] = s0[r]; sreg[bf][4 + r] = s1[r]; }
        }

        const h8* wj = wp + (size_t)j * NIP * 2 * 64 + l;
        h8 A0 = wj[(size_t)ip0 * 128];
        h8 A1 = wj[(size_t)ip0 * 128 + 64];

#pragma unroll 1
        for (int ipl = 0; ipl < 4; ++ipl) {
            const int ipg = ip0 + ipl;
            const int nip = (ipl < 3) ? ipg + 1 : ipg;
            h8 nA0 = wj[(size_t)nip * 128];
            h8 nA1 = wj[(size_t)nip * 128 + 64];

            const h8* xpb = xp + (size_t)ipg * 4 * 64 + l;

#pragma unroll
            for (int half = 0; half < 2; ++half) {
                f4 D[2][4];
#pragma unroll
                for (int pf = 0; pf < 2; ++pf)
#pragma unroll
                    for (int bf = 0; bf < 4; ++bf) { f4 Z = {0.f, 0.f, 0.f, 0.f}; D[pf][bf] = Z; }
#pragma unroll
                for (int bfp = 0; bfp < 2; ++bfp) {
                    const h8 Ba = xpb[(2 * bfp) * 64];
                    const h8 Bb = xpb[(2 * bfp + 1) * 64];
                    const h8 Bma = ((half == 0) == lo) ? zh : Ba;
                    const h8 Bmb = ((half == 0) == lo) ? zh : Bb;
                    D[0][2 * bfp]     = __builtin_amdgcn_mfma_f32_16x16x32_f16(A0, Bma, D[0][2 * bfp], 0, 0, 0);
                    D[1][2 * bfp]     = __builtin_amdgcn_mfma_f32_16x16x32_f16(A1, Bma, D[1][2 * bfp], 0, 0, 0);
                    D[0][2 * bfp + 1] = __builtin_amdgcn_mfma_f32_16x16x32_f16(A0, Bmb, D[0][2 * bfp + 1], 0, 0, 0);
                    D[1][2 * bfp + 1] = __builtin_amdgcn_mfma_f32_16x16x32_f16(A1, Bmb, D[1][2 * bfp + 1], 0, 0, 0);
                }
                float part[4];
#pragma unroll
                for (int bf = 0; bf < 4; ++bf) {
                    float p_ = 0.f;
#pragma unroll
                    for (int pf = 0; pf < 2; ++pf)
#pragma unroll
                        for (int r = 0; r < 4; ++r) p_ += sreg[bf][pf * 4 + r] * D[pf][bf][r];
                    p_ += __shfl_xor(p_, 16);
                    p_ += __shfl_xor(p_, 32);
                    part[bf] = p_;
                }
                const int hb = l >> 4;
                const float wval = hb == 0 ? part[0] : hb == 1 ? part[1] : hb == 2 ? part[2] : part[3];
                L[ipl * 2 + half][j][(l & 15) + 16 * hb] = wval;
            }
            A0 = nA0; A1 = nA1;
        }
    }
    __syncthreads();

    {
        const int b = t & 63, ii = t >> 6;
        float lv[32];
        float m = -1e30f;
#pragma unroll
        for (int j = 0; j < 32; ++j) { lv[j] = L[ii][j][b]; m = fmaxf(m, lv[j]); }
        float s = 0.f;
#pragma unroll
        for (int j = 0; j < 32; ++j) { lv[j] = __expf(lv[j] - m); s += lv[j]; }
        const float inv = 1.f / s;
#pragma unroll
        for (int j = 0; j < 32; ++j) L[ii][j][b] = lv[j] * inv;
    }
    __syncthreads();

    {
        const int jw = t >> 4, r = t & 15;
#pragma unroll 1
        for (int ii = 0; ii < 8; ++ii) {
            h4 c4;
#pragma unroll
            for (int e = 0; e < 4; ++e) c4[e] = (_Float16)L[ii][jw][16 * e + r];
            *reinterpret_cast<h4*>(cp + ((size_t)jw * NI + i0 + ii) * 64 + r * 4) = c4;
        }
    }
}

// K2 (R14): ACC[b,j,p] += sum_i c[b,j,i]*hat[b,j,i,p], TWO j per block.
// grid 512 = (jp 0..15)*32 + (is 0..31); stripe = 32 ipairs; wave wv owns
// 4 ipairs and BOTH j's — B (xp) loaded once, used by both j's MFMAs.
__global__ __launch_bounds__(512)
void accum_kernel(const h8* __restrict__ wp, const h8* __restrict__ xp,
                  const _Float16* __restrict__ cp, float* __restrict__ ACC)
{
    const int t = threadIdx.x, wv = t >> 6, l = t & 63;
    const int jp = blockIdx.x >> 5, is = blockIdx.x & 31;
    const int j0 = jp * 2;
    const int ioff = (l >= 32) ? 1 : 0;

    f4 D[2][2][4];   // [jj][pf][bf]
#pragma unroll
    for (int jj = 0; jj < 2; ++jj)
#pragma unroll
        for (int pf = 0; pf < 2; ++pf)
#pragma unroll
            for (int bf = 0; bf < 4; ++bf) { f4 Z = {0.f, 0.f, 0.f, 0.f}; D[jj][pf][bf] = Z; }

    const int pbase = is * 32 + wv * 4;
    const h8* wj0 = wp + (size_t)j0 * NIP * 2 * 64 + l;
    const h8* wj1 = wj0 + (size_t)NIP * 2 * 64;
    const _Float16* cj0 = cp + ((size_t)j0 * NI + ioff) * 64 + (l & 15) * 4;
    const _Float16* cj1 = cj0 + (size_t)NI * 64;

#pragma unroll 1
    for (int ipl = 0; ipl < 4; ++ipl) {
        const int ipg = pbase + ipl;
        // shared B stream (one load, two j consumers)
        const h8* xpb = xp + (size_t)ipg * 4 * 64 + l;
        const h8 B0 = xpb[0], B1 = xpb[64], B2 = xpb[128], B3 = xpb[192];
        // per-j A fragments + c
        const h8 A00 = wj0[(size_t)ipg * 128];
        const h8 A01 = wj0[(size_t)ipg * 128 + 64];
        const h8 A10 = wj1[(size_t)ipg * 128];
        const h8 A11 = wj1[(size_t)ipg * 128 + 64];
        const h4 c0 = *reinterpret_cast<const h4*>(cj0 + (size_t)(2 * ipg) * 64);
        const h4 c1 = *reinterpret_cast<const h4*>(cj1 + (size_t)(2 * ipg) * 64);

        {
            const h8 b0 = B0 * c0[0], b1 = B1 * c0[1], b2 = B2 * c0[2], b3 = B3 * c0[3];
            D[0][0][0] = __builtin_amdgcn_mfma_f32_16x16x32_f16(A00, b0, D[0][0][0], 0, 0, 0);
            D[0][1][0] = __builtin_amdgcn_mfma_f32_16x16x32_f16(A01, b0, D[0][1][0], 0, 0, 0);
            D[0][0][1] = __builtin_amdgcn_mfma_f32_16x16x32_f16(A00, b1, D[0][0][1], 0, 0, 0);
            D[0][1][1] = __builtin_amdgcn_mfma_f32_16x16x32_f16(A01, b1, D[0][1][1], 0, 0, 0);
            D[0][0][2] = __builtin_amdgcn_mfma_f32_16x16x32_f16(A00, b2, D[0][0][2], 0, 0, 0);
            D[0][1][2] = __builtin_amdgcn_mfma_f32_16x16x32_f16(A01, b2, D[0][1][2], 0, 0, 0);
            D[0][0][3] = __builtin_amdgcn_mfma_f32_16x16x32_f16(A00, b3, D[0][0][3], 0, 0, 0);
            D[0][1][3] = __builtin_amdgcn_mfma_f32_16x16x32_f16(A01, b3, D[0][1][3], 0, 0, 0);
        }
        {
            const h8 b0 = B0 * c1[0], b1 = B1 * c1[1], b2 = B2 * c1[2], b3 = B3 * c1[3];
            D[1][0][0] = __builtin_amdgcn_mfma_f32_16x16x32_f16(A10, b0, D[1][0][0], 0, 0, 0);
            D[1][1][0] = __builtin_amdgcn_mfma_f32_16x16x32_f16(A11, b0, D[1][1][0], 0, 0, 0);
            D[1][0][1] = __builtin_amdgcn_mfma_f32_16x16x32_f16(A10, b1, D[1][0][1], 0, 0, 0);
            D[1][1][1] = __builtin_amdgcn_mfma_f32_16x16x32_f16(A11, b1, D[1][1][1], 0, 0, 0);
            D[1][0][2] = __builtin_amdgcn_mfma_f32_16x16x32_f16(A10, b2, D[1][0][2], 0, 0, 0);
            D[1][1][2] = __builtin_amdgcn_mfma_f32_16x16x32_f16(A11, b2, D[1][1][2], 0, 0, 0);
            D[1][0][3] = __builtin_amdgcn_mfma_f32_16x16x32_f16(A10, b3, D[1][0][3], 0, 0, 0);
            D[1][1][3] = __builtin_amdgcn_mfma_f32_16x16x32_f16(A11, b3, D[1][1][3], 0, 0, 0);
        }
    }

    // epilogue: one shared R buffer, two sequential rounds (j0 then j1)
    __shared__ float R[8][64 * 36];
#pragma unroll 1
    for (int jj = 0; jj < 2; ++jj) {
        if (jj) __syncthreads();   // protect R reuse
#pragma unroll
        for (int pf = 0; pf < 2; ++pf)
#pragma unroll
            for (int bf = 0; bf < 4; ++bf) {
                const int b = (l & 15) + 16 * bf, p = (l >> 4) * 4 + 16 * pf;
                *reinterpret_cast<f4*>(&R[wv][b * 36 + p]) = D[jj][pf][bf];
            }
        __syncthreads();
#pragma unroll
        for (int k = 0; k < 4; ++k) {
            const int id = t + k * 512;
            const int b = id >> 5, p = id & 31;
            float s = 0.f;
#pragma unroll
            for (int w8 = 0; w8 < 8; ++w8) s += R[w8][b * 36 + p];
            atomicAdd(ACC + ((size_t)b * NJ + (j0 + jj)) * NP + p, s);
        }
    }
}

// OUT = squash(U*scale) (+ ADD) over last axis (P=32)
__global__ __launch_bounds__(256)
void squash_kernel(const float* __restrict__ U, const float* __restrict__ ADD,
                   float* __restrict__ OUT, float scale)
{
    const int t   = threadIdx.x;
    const int row = blockIdx.x * 8 + (t >> 5);
    const int p   = t & 31;
    const float val = U[row * 32 + p] * scale;
    float sq = val * val;
#pragma unroll
    for (int d = 1; d < 32; d <<= 1) sq += __shfl_xor(sq, d);
    float o = val * sqscale(sq);
    if (ADD != nullptr) o += ADD[row * 32 + p];
    OUT[row * 32 + p] = o;
}

extern "C" void kernel_launch(void* const* d_in, const int* in_sizes, int n_in,
                              void* d_out, int out_size, void* d_ws, size_t ws_size,
                              hipStream_t stream)
{
    const float* X  = (const float*)d_in[0];   // [64, 2048, 16]
    const float* Wg = (const float*)d_in[1];   // [32, 2048, 32, 16]
    float* out = (float*)d_out;                // [64, 32, 32]

    // ws: v1u,v2u,ou (768 KB, zeroed) | S2,S3 (512 KB) | xp 4 MB | cp 8 MB | wp 64 MB
    float* v1u = (float*)d_ws;
    float* v2u = v1u + VSZ;
    float* ou  = v2u + VSZ;
    float* S2  = ou  + VSZ;
    float* S3  = S2  + VSZ;
    h8* xp = (h8*)((char*)d_ws + (size_t)5 * VSZ * 4);
    _Float16* cp = (_Float16*)((char*)xp + (size_t)NIP * 4 * 64 * 16);
    h8* wpk = (h8*)((char*)cp + (size_t)NJ * NI * 64 * 2);

    xpack_kernel<<<NIP, 256, 0, stream>>>(X, xp);
    zero_kernel<<<3 * VSZ * 4 / (256 * 16), 256, 0, stream>>>((f4*)d_ws);

    // pass A fused with W packing: wp + v1u
    wacc_kernel<<<512, 512, 0, stream>>>(Wg, xp, wpk, v1u);

    // iter 2: S2 = squash(v1u/32); logits -> cp; weighted accum -> v2u
    squash_kernel<<<VSZ / 256, 256, 0, stream>>>(v1u, nullptr, S2, 1.f / 32.f);
    logits_kernel<<<NI / 8, 512, 0, stream>>>(wpk, xp, S2, cp);
    accum_kernel<<<512, 512, 0, stream>>>(wpk, xp, cp, v2u);

    // iter 3: S3 = squash(v2u) + S2; logits -> cp; accum -> ou
    squash_kernel<<<VSZ / 256, 256, 0, stream>>>(v2u, S2, S3, 1.f);
    logits_kernel<<<NI / 8, 512, 0, stream>>>(wpk, xp, S3, cp);
    accum_kernel<<<512, 512, 0, stream>>>(wpk, xp, cp, ou);

    squash_kernel<<<VSZ / 256, 256, 0, stream>>>(ou, nullptr, out, 1.f);
}

// Round 15
// 136.374 us; speedup vs baseline: 1.3607x; 1.3607x over previous
//
#include <hip/hip_runtime.h>

typedef _Float16 h8 __attribute__((ext_vector_type(8)));
typedef _Float16 h4 __attribute__((ext_vector_type(4)));
typedef float f4 __attribute__((ext_vector_type(4)));

constexpr int NB = 64;     // batch
constexpr int NI = 2048;   // input capsules
constexpr int NQ = 16;     // input dim
constexpr int NJ = 32;     // num capsules
constexpr int NP = 32;     // dim capsule
constexpr int NIP = NI / 2;         // 1024 i-pairs
constexpr int VSZ = NB * NJ * NP;   // 65536 per v-buffer

// ---------------------------------------------------------------------------
// MFMA plan (single-f16 W, i-PAIRED K):
//   per (j, ipair): D[p16,b16] += over K=32: k<16 -> W[j,i_e,p,q=k]*x[b,i_e,q]
//                                      k>=16 -> W[j,i_o,p,q=k-16]*x[b,i_o,q]
//   A lane layout: row p=l&15 (pf frag adds +16), i = l>=32 ? i_o : i_e
//   B lane layout: col b=(l&15)+16bf, same (i,q) lane split as A
//   D lane layout: col b=l&15, row p=(l>>4)*4+reg (+16 per pf)
// R15 = R12 (136.35us best) + ONE change: accum epilogue uses a two-round
// cross-wave reduce (R[4] = 36 KB instead of R[8] = 72 KB), shrinking the
// SMEM union (staging 48 KB | R 36 KB) to 48 KB -> 3 blocks/CU.
// ---------------------------------------------------------------------------

__global__ __launch_bounds__(256)
void zero_kernel(f4* __restrict__ p)
{
    const f4 z = {0.f, 0.f, 0.f, 0.f};
    p[(size_t)blockIdx.x * 256 + threadIdx.x] = z;
}

// x pack, paired: xp[(ip*4+bf)*64 + l] = x[b=(l&15)+16bf, i=2ip+(l>=32), q0..q0+7]
__global__ __launch_bounds__(256)
void xpack_kernel(const float* __restrict__ X, h8* __restrict__ xp)
{
    const int ip = blockIdx.x;
    const int t = threadIdx.x;
    const int bf = t >> 6, l = t & 63;
    const int b = (l & 15) + 16 * bf;
    const int i = 2 * ip + (l >= 32 ? 1 : 0);
    const int q0 = ((l >> 4) & 1) * 8;
    const float* xs = X + ((size_t)b * NI + i) * NQ + q0;
    const float4 u = *reinterpret_cast<const float4*>(xs);
    const float4 v = *reinterpret_cast<const float4*>(xs + 4);
    h8 h;
    h[0] = (_Float16)u.x; h[1] = (_Float16)u.y; h[2] = (_Float16)u.z; h[3] = (_Float16)u.w;
    h[4] = (_Float16)v.x; h[5] = (_Float16)v.y; h[6] = (_Float16)v.z; h[7] = (_Float16)v.w;
    xp[(size_t)(ip * 4 + bf) * 64 + l] = h;
}

__device__ inline float sqscale(float s2)
{
    return s2 / ((1.f + s2) * sqrtf(s2 + 1e-7f));
}

// K0: fused W pack + pass-A uniform accumulation.  (R11/R12 verbatim)
__global__ __launch_bounds__(512)
void wacc_kernel(const float* __restrict__ Wg, const h8* __restrict__ xp,
                 h8* __restrict__ wp, float* __restrict__ ACC)
{
    const int t = threadIdx.x, wv = t >> 6, l = t & 63;
    const int j = blockIdx.x >> 4, is = blockIdx.x & 15;
    const int ioff = (l >= 32) ? 1 : 0;
    const int q0 = ((l >> 4) & 1) * 8;
    const int pbase = is * 64 + wv * 8;

    f4 D[2][4];
#pragma unroll
    for (int pf = 0; pf < 2; ++pf)
#pragma unroll
        for (int bf = 0; bf < 4; ++bf) { f4 Z = {0.f, 0.f, 0.f, 0.f}; D[pf][bf] = Z; }

    const float* wgl = Wg + ((size_t)j * NI + ioff) * (NP * NQ) + (size_t)(l & 15) * NQ + q0;

    f4 u0, u1, v0, v1;
    {
        const float* s0 = wgl + (size_t)(2 * pbase) * (NP * NQ);
        u0 = *reinterpret_cast<const f4*>(s0);
        u1 = *reinterpret_cast<const f4*>(s0 + 4);
        v0 = *reinterpret_cast<const f4*>(s0 + 16 * NQ);
        v1 = *reinterpret_cast<const f4*>(s0 + 16 * NQ + 4);
    }
    h8 B0, B1, B2, B3;
    {
        const h8* xpb = xp + (size_t)pbase * 4 * 64 + l;
        B0 = xpb[0]; B1 = xpb[64]; B2 = xpb[128]; B3 = xpb[192];
    }

#pragma unroll 1
    for (int ipl = 0; ipl < 8; ++ipl) {
        const int ipg = pbase + ipl;
        const int nip = (ipl < 7) ? ipg + 1 : ipg;
        f4 nu0, nu1, nv0, nv1;
        {
            const float* s0 = wgl + (size_t)(2 * nip) * (NP * NQ);
            nu0 = *reinterpret_cast<const f4*>(s0);
            nu1 = *reinterpret_cast<const f4*>(s0 + 4);
            nv0 = *reinterpret_cast<const f4*>(s0 + 16 * NQ);
            nv1 = *reinterpret_cast<const f4*>(s0 + 16 * NQ + 4);
        }
        h8 nB0, nB1, nB2, nB3;
        {
            const h8* xpb = xp + (size_t)nip * 4 * 64 + l;
            nB0 = xpb[0]; nB1 = xpb[64]; nB2 = xpb[128]; nB3 = xpb[192];
        }

        h8 A0, A1;
#pragma unroll
        for (int e = 0; e < 4; ++e) {
            A0[e] = (_Float16)u0[e]; A0[e + 4] = (_Float16)u1[e];
            A1[e] = (_Float16)v0[e]; A1[e + 4] = (_Float16)v1[e];
        }
        const size_t wo = ((size_t)j * NIP + ipg) * 2 * 64 + l;
        wp[wo] = A0;
        wp[wo + 64] = A1;
        D[0][0] = __builtin_amdgcn_mfma_f32_16x16x32_f16(A0, B0, D[0][0], 0, 0, 0);
        D[1][0] = __builtin_amdgcn_mfma_f32_16x16x32_f16(A1, B0, D[1][0], 0, 0, 0);
        D[0][1] = __builtin_amdgcn_mfma_f32_16x16x32_f16(A0, B1, D[0][1], 0, 0, 0);
        D[1][1] = __builtin_amdgcn_mfma_f32_16x16x32_f16(A1, B1, D[1][1], 0, 0, 0);
        D[0][2] = __builtin_amdgcn_mfma_f32_16x16x32_f16(A0, B2, D[0][2], 0, 0, 0);
        D[1][2] = __builtin_amdgcn_mfma_f32_16x16x32_f16(A1, B2, D[1][2], 0, 0, 0);
        D[0][3] = __builtin_amdgcn_mfma_f32_16x16x32_f16(A0, B3, D[0][3], 0, 0, 0);
        D[1][3] = __builtin_amdgcn_mfma_f32_16x16x32_f16(A1, B3, D[1][3], 0, 0, 0);
        u0 = nu0; u1 = nu1; v0 = nv0; v1 = nv1;
        B0 = nB0; B1 = nB1; B2 = nB2; B3 = nB3;
    }

    __shared__ float R[8][64 * 36];
#pragma unroll
    for (int pf = 0; pf < 2; ++pf)
#pragma unroll
        for (int bf = 0; bf < 4; ++bf) {
            const int b = (l & 15) + 16 * bf, p = (l >> 4) * 4 + 16 * pf;
            *reinterpret_cast<f4*>(&R[wv][b * 36 + p]) = D[pf][bf];
        }
    __syncthreads();
#pragma unroll
    for (int k = 0; k < 4; ++k) {
        const int id = t + k * 512;
        const int b = id >> 5, p = id & 31;
        float s = 0.f;
#pragma unroll
        for (int w8 = 0; w8 < 8; ++w8) s += R[w8][b * 36 + p];
        atomicAdd(ACC + ((size_t)b * NJ + j) * NP + p, s);
    }
}

// K1: logits + softmax -> c (f16). S pre-squashed.  (R11/R12 verbatim)
__global__ __launch_bounds__(512)
void logits_kernel(const h8* __restrict__ wp, const h8* __restrict__ xp,
                   const float* __restrict__ S, _Float16* __restrict__ cp)
{
    __shared__ float L[8][32][64];
    const int t = threadIdx.x, wv = t >> 6, l = t & 63;
    const int i0 = blockIdx.x * 8;
    const int ip0 = blockIdx.x * 4;
    const bool lo = l >= 32;
    h8 zh;
#pragma unroll
    for (int e = 0; e < 8; ++e) zh[e] = (_Float16)0.f;

#pragma unroll 1
    for (int jj = 0; jj < 4; ++jj) {
        const int j = wv * 4 + jj;

        float sreg[4][8];
#pragma unroll
        for (int bf = 0; bf < 4; ++bf) {
            const int b = (l & 15) + 16 * bf;
            const size_t base = ((size_t)b * NJ + j) * NP + (l >> 4) * 4;
            const f4 s0 = *reinterpret_cast<const f4*>(S + base);
            const f4 s1 = *reinterpret_cast<const f4*>(S + base + 16);
#pragma unroll
            for (int r = 0; r < 4; ++r) { sreg[bf][r] = s0[r]; sreg[bf][4 + r] = s1[r]; }
        }

        const h8* wj = wp + (size_t)j * NIP * 2 * 64 + l;
        h8 A0 = wj[(size_t)ip0 * 128];
        h8 A1 = wj[(size_t)ip0 * 128 + 64];

#pragma unroll 1
        for (int ipl = 0; ipl < 4; ++ipl) {
            const int ipg = ip0 + ipl;
            const int nip = (ipl < 3) ? ipg + 1 : ipg;
            h8 nA0 = wj[(size_t)nip * 128];
            h8 nA1 = wj[(size_t)nip * 128 + 64];

            const h8* xpb = xp + (size_t)ipg * 4 * 64 + l;

#pragma unroll
            for (int half = 0; half < 2; ++half) {
                f4 D[2][4];
#pragma unroll
                for (int pf = 0; pf < 2; ++pf)
#pragma unroll
                    for (int bf = 0; bf < 4; ++bf) { f4 Z = {0.f, 0.f, 0.f, 0.f}; D[pf][bf] = Z; }
#pragma unroll
                for (int bfp = 0; bfp < 2; ++bfp) {
                    const h8 Ba = xpb[(2 * bfp) * 64];
                    const h8 Bb = xpb[(2 * bfp + 1) * 64];
                    const h8 Bma = ((half == 0) == lo) ? zh : Ba;
                    const h8 Bmb = ((half == 0) == lo) ? zh : Bb;
                    D[0][2 * bfp]     = __builtin_amdgcn_mfma_f32_16x16x32_f16(A0, Bma, D[0][2 * bfp], 0, 0, 0);
                    D[1][2 * bfp]     = __builtin_amdgcn_mfma_f32_16x16x32_f16(A1, Bma, D[1][2 * bfp], 0, 0, 0);
                    D[0][2 * bfp + 1] = __builtin_amdgcn_mfma_f32_16x16x32_f16(A0, Bmb, D[0][2 * bfp + 1], 0, 0, 0);
                    D[1][2 * bfp + 1] = __builtin_amdgcn_mfma_f32_16x16x32_f16(A1, Bmb, D[1][2 * bfp + 1], 0, 0, 0);
                }
                float part[4];
#pragma unroll
                for (int bf = 0; bf < 4; ++bf) {
                    float p_ = 0.f;
#pragma unroll
                    for (int pf = 0; pf < 2; ++pf)
#pragma unroll
                        for (int r = 0; r < 4; ++r) p_ += sreg[bf][pf * 4 + r] * D[pf][bf][r];
                    p_ += __shfl_xor(p_, 16);
                    p_ += __shfl_xor(p_, 32);
                    part[bf] = p_;
                }
                const int hb = l >> 4;
                const float wval = hb == 0 ? part[0] : hb == 1 ? part[1] : hb == 2 ? part[2] : part[3];
                L[ipl * 2 + half][j][(l & 15) + 16 * hb] = wval;
            }
            A0 = nA0; A1 = nA1;
        }
    }
    __syncthreads();

    {
        const int b = t & 63, ii = t >> 6;
        float lv[32];
        float m = -1e30f;
#pragma unroll
        for (int j = 0; j < 32; ++j) { lv[j] = L[ii][j][b]; m = fmaxf(m, lv[j]); }
        float s = 0.f;
#pragma unroll
        for (int j = 0; j < 32; ++j) { lv[j] = __expf(lv[j] - m); s += lv[j]; }
        const float inv = 1.f / s;
#pragma unroll
        for (int j = 0; j < 32; ++j) L[ii][j][b] = lv[j] * inv;
    }
    __syncthreads();

    {
        const int jw = t >> 4, r = t & 15;
#pragma unroll 1
        for (int ii = 0; ii < 8; ++ii) {
            h4 c4;
#pragma unroll
            for (int e = 0; e < 4; ++e) c4[e] = (_Float16)L[ii][jw][16 * e + r];
            *reinterpret_cast<h4*>(cp + ((size_t)jw * NI + i0 + ii) * 64 + r * 4) = c4;
        }
    }
}

// K2: ACC[b,j,p] += sum_i c[b,j,i]*hat[b,j,i,p]
// R15: R12's LDS-staged A stream (3 slots x 2 KB/wave, counted vmcnt) +
// two-round cross-wave reduce epilogue -> SMEM union 48 KB -> 3 blocks/CU.
__global__ __launch_bounds__(512)
void accum_kernel(const h8* __restrict__ wp, const h8* __restrict__ xp,
                  const _Float16* __restrict__ cp, float* __restrict__ ACC)
{
    __shared__ char SMEM[49152];   // staging 48 KB | epilogue R[4][64*36] 36 KB
    const int t = threadIdx.x, wv = t >> 6, l = t & 63;
    const int j = blockIdx.x >> 4, is = blockIdx.x & 15;
    const int ioff = (l >= 32) ? 1 : 0;

    f4 D[2][4];
#pragma unroll
    for (int pf = 0; pf < 2; ++pf)
#pragma unroll
        for (int bf = 0; bf < 4; ++bf) { f4 Z = {0.f, 0.f, 0.f, 0.f}; D[pf][bf] = Z; }

    const int pbase = is * 64 + wv * 8;
    const h8* wj = wp + (size_t)j * NIP * 2 * 64 + l;   // lane-resolved ptr
    const _Float16* cj = cp + ((size_t)j * NI + ioff) * 64 + (l & 15) * 4;

    char* stg = SMEM + wv * 6144;   // 3 slots x 2048 B, wave-private

    auto STAGE = [&](int ipl) {
        const int slot = ipl % 3;
        const h8* src = wj + (size_t)(pbase + ipl) * 128;
        __builtin_amdgcn_global_load_lds(
            (const __attribute__((address_space(1))) void*)(src),
            (__attribute__((address_space(3))) void*)(stg + slot * 2048), 16, 0, 0);
        __builtin_amdgcn_global_load_lds(
            (const __attribute__((address_space(1))) void*)(src + 64),
            (__attribute__((address_space(3))) void*)(stg + slot * 2048 + 1024), 16, 0, 0);
    };

    STAGE(0);
    STAGE(1);

#pragma unroll 1
    for (int ipl = 0; ipl < 8; ++ipl) {
        const int ipg = pbase + ipl;
        if (ipl + 2 < 8) STAGE(ipl + 2);

        if (ipl < 6)       asm volatile("s_waitcnt vmcnt(4)" ::: "memory");
        else if (ipl == 6) asm volatile("s_waitcnt vmcnt(2)" ::: "memory");
        else               asm volatile("s_waitcnt vmcnt(0)" ::: "memory");
        __builtin_amdgcn_sched_barrier(0);

        const int slot = ipl % 3;
        const h8 A0 = *reinterpret_cast<const h8*>(stg + slot * 2048 + l * 16);
        const h8 A1 = *reinterpret_cast<const h8*>(stg + slot * 2048 + 1024 + l * 16);

        const h8* xpb = xp + (size_t)ipg * 4 * 64 + l;
        const h4 c4 = *reinterpret_cast<const h4*>(cj + (size_t)(2 * ipg) * 64);
        const h8 b0 = xpb[0] * c4[0];
        const h8 b1 = xpb[64] * c4[1];
        const h8 b2 = xpb[128] * c4[2];
        const h8 b3 = xpb[192] * c4[3];

        D[0][0] = __builtin_amdgcn_mfma_f32_16x16x32_f16(A0, b0, D[0][0], 0, 0, 0);
        D[1][0] = __builtin_amdgcn_mfma_f32_16x16x32_f16(A1, b0, D[1][0], 0, 0, 0);
        D[0][1] = __builtin_amdgcn_mfma_f32_16x16x32_f16(A0, b1, D[0][1], 0, 0, 0);
        D[1][1] = __builtin_amdgcn_mfma_f32_16x16x32_f16(A1, b1, D[1][1], 0, 0, 0);
        D[0][2] = __builtin_amdgcn_mfma_f32_16x16x32_f16(A0, b2, D[0][2], 0, 0, 0);
        D[1][2] = __builtin_amdgcn_mfma_f32_16x16x32_f16(A1, b2, D[1][2], 0, 0, 0);
        D[0][3] = __builtin_amdgcn_mfma_f32_16x16x32_f16(A0, b3, D[0][3], 0, 0, 0);
        D[1][3] = __builtin_amdgcn_mfma_f32_16x16x32_f16(A1, b3, D[1][3], 0, 0, 0);
    }

    // epilogue: two-round cross-wave reduce in R[4][64*36] (36 KB)
    __syncthreads();   // all staging consumed before SMEM reuse
    float (*R)[64 * 36] = reinterpret_cast<float (*)[64 * 36]>(SMEM);
    if (wv < 4) {
#pragma unroll
        for (int pf = 0; pf < 2; ++pf)
#pragma unroll
            for (int bf = 0; bf < 4; ++bf) {
                const int b = (l & 15) + 16 * bf, p = (l >> 4) * 4 + 16 * pf;
                *reinterpret_cast<f4*>(&R[wv][b * 36 + p]) = D[pf][bf];
            }
    }
    __syncthreads();
    if (wv >= 4) {
#pragma unroll
        for (int pf = 0; pf < 2; ++pf)
#pragma unroll
            for (int bf = 0; bf < 4; ++bf) {
                const int b = (l & 15) + 16 * bf, p = (l >> 4) * 4 + 16 * pf;
                f4* dst = reinterpret_cast<f4*>(&R[wv - 4][b * 36 + p]);
                *dst = *dst + D[pf][bf];
            }
    }
    __syncthreads();
#pragma unroll
    for (int k = 0; k < 4; ++k) {
        const int id = t + k * 512;
        const int b = id >> 5, p = id & 31;
        float s = 0.f;
#pragma unroll
        for (int w4 = 0; w4 < 4; ++w4) s += R[w4][b * 36 + p];
        atomicAdd(ACC + ((size_t)b * NJ + j) * NP + p, s);
    }
}

// OUT = squash(U*scale) (+ ADD) over last axis (P=32)
__global__ __launch_bounds__(256)
void squash_kernel(const float* __restrict__ U, const float* __restrict__ ADD,
                   float* __restrict__ OUT, float scale)
{
    const int t   = threadIdx.x;
    const int row = blockIdx.x * 8 + (t >> 5);
    const int p   = t & 31;
    const float val = U[row * 32 + p] * scale;
    float sq = val * val;
#pragma unroll
    for (int d = 1; d < 32; d <<= 1) sq += __shfl_xor(sq, d);
    float o = val * sqscale(sq);
    if (ADD != nullptr) o += ADD[row * 32 + p];
    OUT[row * 32 + p] = o;
}

extern "C" void kernel_launch(void* const* d_in, const int* in_sizes, int n_in,
                              void* d_out, int out_size, void* d_ws, size_t ws_size,
                              hipStream_t stream)
{
    const float* X  = (const float*)d_in[0];   // [64, 2048, 16]
    const float* Wg = (const float*)d_in[1];   // [32, 2048, 32, 16]
    float* out = (float*)d_out;                // [64, 32, 32]

    // ws: v1u,v2u,ou (768 KB, zeroed) | S2,S3 (512 KB) | xp 4 MB | cp 8 MB | wp 64 MB
    float* v1u = (float*)d_ws;
    float* v2u = v1u + VSZ;
    float* ou  = v2u + VSZ;
    float* S2  = ou  + VSZ;
    float* S3  = S2  + VSZ;
    h8* xp = (h8*)((char*)d_ws + (size_t)5 * VSZ * 4);
    _Float16* cp = (_Float16*)((char*)xp + (size_t)NIP * 4 * 64 * 16);
    h8* wpk = (h8*)((char*)cp + (size_t)NJ * NI * 64 * 2);

    xpack_kernel<<<NIP, 256, 0, stream>>>(X, xp);
    zero_kernel<<<3 * VSZ * 4 / (256 * 16), 256, 0, stream>>>((f4*)d_ws);

    // pass A fused with W packing: wp + v1u
    wacc_kernel<<<512, 512, 0, stream>>>(Wg, xp, wpk, v1u);

    // iter 2: S2 = squash(v1u/32); logits -> cp; weighted accum -> v2u
    squash_kernel<<<VSZ / 256, 256, 0, stream>>>(v1u, nullptr, S2, 1.f / 32.f);
    logits_kernel<<<NI / 8, 512, 0, stream>>>(wpk, xp, S2, cp);
    accum_kernel<<<512, 512, 0, stream>>>(wpk, xp, cp, v2u);

    // iter 3: S3 = squash(v2u) + S2; logits -> cp; accum -> ou
    squash_kernel<<<VSZ / 256, 256, 0, stream>>>(v2u, S2, S3, 1.f);
    logits_kernel<<<NI / 8, 512, 0, stream>>>(wpk, xp, S3, cp);
    accum_kernel<<<512, 512, 0, stream>>>(wpk, xp, cp, ou);

    squash_kernel<<<VSZ / 256, 256, 0, stream>>>(ou, nullptr, out, 1.f);
}

// Round 16
// 135.659 us; speedup vs baseline: 1.3679x; 1.0053x over previous
//
#include <hip/hip_runtime.h>

typedef _Float16 h8 __attribute__((ext_vector_type(8)));
typedef _Float16 h4 __attribute__((ext_vector_type(4)));
typedef float f4 __attribute__((ext_vector_type(4)));

constexpr int NB = 64;     // batch
constexpr int NI = 2048;   // input capsules
constexpr int NQ = 16;     // input dim
constexpr int NJ = 32;     // num capsules
constexpr int NP = 32;     // dim capsule
constexpr int NIP = NI / 2;         // 1024 i-pairs
constexpr int VSZ = NB * NJ * NP;   // 65536 per v-buffer
constexpr int ZBLK = 16;            // zero-sweep tail blocks on xpack grid

// ---------------------------------------------------------------------------
// MFMA plan (single-f16 W, i-PAIRED K):
//   per (j, ipair): D[p16,b16] += over K=32: k<16 -> W[j,i_e,p,q=k]*x[b,i_e,q]
//                                      k>=16 -> W[j,i_o,p,q=k-16]*x[b,i_o,q]
//   A lane layout: row p=l&15 (pf frag adds +16), i = l>=32 ? i_o : i_e
//   B lane layout: col b=(l&15)+16bf, same (i,q) lane split as A
//   D lane layout: col b=l&15, row p=(l>>4)*4+reg (+16 per pf)
// R16 = R15 (tied best 136.37) + ONE change: zero sweep merged into xpack
// as tail blocks (9 -> 8 launches). All compute kernels byte-identical.
// ---------------------------------------------------------------------------

// x pack, paired: xp[(ip*4+bf)*64 + l] = x[b=(l&15)+16bf, i=2ip+(l>=32), q0..q0+7]
// Tail blocks (bid >= NIP) zero the 3*VSZ accumulator region (768 KB).
__global__ __launch_bounds__(256)
void xpack_kernel(const float* __restrict__ X, h8* __restrict__ xp,
                  f4* __restrict__ zbase)
{
    const int bid = blockIdx.x;
    const int t = threadIdx.x;
    if (bid >= NIP) {   // zero sweep: 16 blocks x 256 thr x 12 f4 = 768 KB
        const f4 z = {0.f, 0.f, 0.f, 0.f};
        const int base = (bid - NIP) * 256 + t;
#pragma unroll
        for (int k = 0; k < 12; ++k) zbase[base + k * 4096] = z;
        return;
    }
    const int ip = bid;
    const int bf = t >> 6, l = t & 63;
    const int b = (l & 15) + 16 * bf;
    const int i = 2 * ip + (l >= 32 ? 1 : 0);
    const int q0 = ((l >> 4) & 1) * 8;
    const float* xs = X + ((size_t)b * NI + i) * NQ + q0;
    const float4 u = *reinterpret_cast<const float4*>(xs);
    const float4 v = *reinterpret_cast<const float4*>(xs + 4);
    h8 h;
    h[0] = (_Float16)u.x; h[1] = (_Float16)u.y; h[2] = (_Float16)u.z; h[3] = (_Float16)u.w;
    h[4] = (_Float16)v.x; h[5] = (_Float16)v.y; h[6] = (_Float16)v.z; h[7] = (_Float16)v.w;
    xp[(size_t)(ip * 4 + bf) * 64 + l] = h;
}

__device__ inline float sqscale(float s2)
{
    return s2 / ((1.f + s2) * sqrtf(s2 + 1e-7f));
}

// K0: fused W pack + pass-A uniform accumulation.  (R15 verbatim)
__global__ __launch_bounds__(512)
void wacc_kernel(const float* __restrict__ Wg, const h8* __restrict__ xp,
                 h8* __restrict__ wp, float* __restrict__ ACC)
{
    const int t = threadIdx.x, wv = t >> 6, l = t & 63;
    const int j = blockIdx.x >> 4, is = blockIdx.x & 15;
    const int ioff = (l >= 32) ? 1 : 0;
    const int q0 = ((l >> 4) & 1) * 8;
    const int pbase = is * 64 + wv * 8;

    f4 D[2][4];
#pragma unroll
    for (int pf = 0; pf < 2; ++pf)
#pragma unroll
        for (int bf = 0; bf < 4; ++bf) { f4 Z = {0.f, 0.f, 0.f, 0.f}; D[pf][bf] = Z; }

    const float* wgl = Wg + ((size_t)j * NI + ioff) * (NP * NQ) + (size_t)(l & 15) * NQ + q0;

    f4 u0, u1, v0, v1;
    {
        const float* s0 = wgl + (size_t)(2 * pbase) * (NP * NQ);
        u0 = *reinterpret_cast<const f4*>(s0);
        u1 = *reinterpret_cast<const f4*>(s0 + 4);
        v0 = *reinterpret_cast<const f4*>(s0 + 16 * NQ);
        v1 = *reinterpret_cast<const f4*>(s0 + 16 * NQ + 4);
    }
    h8 B0, B1, B2, B3;
    {
        const h8* xpb = xp + (size_t)pbase * 4 * 64 + l;
        B0 = xpb[0]; B1 = xpb[64]; B2 = xpb[128]; B3 = xpb[192];
    }

#pragma unroll 1
    for (int ipl = 0; ipl < 8; ++ipl) {
        const int ipg = pbase + ipl;
        const int nip = (ipl < 7) ? ipg + 1 : ipg;
        f4 nu0, nu1, nv0, nv1;
        {
            const float* s0 = wgl + (size_t)(2 * nip) * (NP * NQ);
            nu0 = *reinterpret_cast<const f4*>(s0);
            nu1 = *reinterpret_cast<const f4*>(s0 + 4);
            nv0 = *reinterpret_cast<const f4*>(s0 + 16 * NQ);
            nv1 = *reinterpret_cast<const f4*>(s0 + 16 * NQ + 4);
        }
        h8 nB0, nB1, nB2, nB3;
        {
            const h8* xpb = xp + (size_t)nip * 4 * 64 + l;
            nB0 = xpb[0]; nB1 = xpb[64]; nB2 = xpb[128]; nB3 = xpb[192];
        }

        h8 A0, A1;
#pragma unroll
        for (int e = 0; e < 4; ++e) {
            A0[e] = (_Float16)u0[e]; A0[e + 4] = (_Float16)u1[e];
            A1[e] = (_Float16)v0[e]; A1[e + 4] = (_Float16)v1[e];
        }
        const size_t wo = ((size_t)j * NIP + ipg) * 2 * 64 + l;
        wp[wo] = A0;
        wp[wo + 64] = A1;
        D[0][0] = __builtin_amdgcn_mfma_f32_16x16x32_f16(A0, B0, D[0][0], 0, 0, 0);
        D[1][0] = __builtin_amdgcn_mfma_f32_16x16x32_f16(A1, B0, D[1][0], 0, 0, 0);
        D[0][1] = __builtin_amdgcn_mfma_f32_16x16x32_f16(A0, B1, D[0][1], 0, 0, 0);
        D[1][1] = __builtin_amdgcn_mfma_f32_16x16x32_f16(A1, B1, D[1][1], 0, 0, 0);
        D[0][2] = __builtin_amdgcn_mfma_f32_16x16x32_f16(A0, B2, D[0][2], 0, 0, 0);
        D[1][2] = __builtin_amdgcn_mfma_f32_16x16x32_f16(A1, B2, D[1][2], 0, 0, 0);
        D[0][3] = __builtin_amdgcn_mfma_f32_16x16x32_f16(A0, B3, D[0][3], 0, 0, 0);
        D[1][3] = __builtin_amdgcn_mfma_f32_16x16x32_f16(A1, B3, D[1][3], 0, 0, 0);
        u0 = nu0; u1 = nu1; v0 = nv0; v1 = nv1;
        B0 = nB0; B1 = nB1; B2 = nB2; B3 = nB3;
    }

    __shared__ float R[8][64 * 36];
#pragma unroll
    for (int pf = 0; pf < 2; ++pf)
#pragma unroll
        for (int bf = 0; bf < 4; ++bf) {
            const int b = (l & 15) + 16 * bf, p = (l >> 4) * 4 + 16 * pf;
            *reinterpret_cast<f4*>(&R[wv][b * 36 + p]) = D[pf][bf];
        }
    __syncthreads();
#pragma unroll
    for (int k = 0; k < 4; ++k) {
        const int id = t + k * 512;
        const int b = id >> 5, p = id & 31;
        float s = 0.f;
#pragma unroll
        for (int w8 = 0; w8 < 8; ++w8) s += R[w8][b * 36 + p];
        atomicAdd(ACC + ((size_t)b * NJ + j) * NP + p, s);
    }
}

// K1: logits + softmax -> c (f16). S pre-squashed.  (R15 verbatim)
__global__ __launch_bounds__(512)
void logits_kernel(const h8* __restrict__ wp, const h8* __restrict__ xp,
                   const float* __restrict__ S, _Float16* __restrict__ cp)
{
    __shared__ float L[8][32][64];
    const int t = threadIdx.x, wv = t >> 6, l = t & 63;
    const int i0 = blockIdx.x * 8;
    const int ip0 = blockIdx.x * 4;
    const bool lo = l >= 32;
    h8 zh;
#pragma unroll
    for (int e = 0; e < 8; ++e) zh[e] = (_Float16)0.f;

#pragma unroll 1
    for (int jj = 0; jj < 4; ++jj) {
        const int j = wv * 4 + jj;

        float sreg[4][8];
#pragma unroll
        for (int bf = 0; bf < 4; ++bf) {
            const int b = (l & 15) + 16 * bf;
            const size_t base = ((size_t)b * NJ + j) * NP + (l >> 4) * 4;
            const f4 s0 = *reinterpret_cast<const f4*>(S + base);
            const f4 s1 = *reinterpret_cast<const f4*>(S + base + 16);
#pragma unroll
            for (int r = 0; r < 4; ++r) { sreg[bf][r] = s0[r]; sreg[bf][4 + r] = s1[r]; }
        }

        const h8* wj = wp + (size_t)j * NIP * 2 * 64 + l;
        h8 A0 = wj[(size_t)ip0 * 128];
        h8 A1 = wj[(size_t)ip0 * 128 + 64];

#pragma unroll 1
        for (int ipl = 0; ipl < 4; ++ipl) {
            const int ipg = ip0 + ipl;
            const int nip = (ipl < 3) ? ipg + 1 : ipg;
            h8 nA0 = wj[(size_t)nip * 128];
            h8 nA1 = wj[(size_t)nip * 128 + 64];

            const h8* xpb = xp + (size_t)ipg * 4 * 64 + l;

#pragma unroll
            for (int half = 0; half < 2; ++half) {
                f4 D[2][4];
#pragma unroll
                for (int pf = 0; pf < 2; ++pf)
#pragma unroll
                    for (int bf = 0; bf < 4; ++bf) { f4 Z = {0.f, 0.f, 0.f, 0.f}; D[pf][bf] = Z; }
#pragma unroll
                for (int bfp = 0; bfp < 2; ++bfp) {
                    const h8 Ba = xpb[(2 * bfp) * 64];
                    const h8 Bb = xpb[(2 * bfp + 1) * 64];
                    const h8 Bma = ((half == 0) == lo) ? zh : Ba;
                    const h8 Bmb = ((half == 0) == lo) ? zh : Bb;
                    D[0][2 * bfp]     = __builtin_amdgcn_mfma_f32_16x16x32_f16(A0, Bma, D[0][2 * bfp], 0, 0, 0);
                    D[1][2 * bfp]     = __builtin_amdgcn_mfma_f32_16x16x32_f16(A1, Bma, D[1][2 * bfp], 0, 0, 0);
                    D[0][2 * bfp + 1] = __builtin_amdgcn_mfma_f32_16x16x32_f16(A0, Bmb, D[0][2 * bfp + 1], 0, 0, 0);
                    D[1][2 * bfp + 1] = __builtin_amdgcn_mfma_f32_16x16x32_f16(A1, Bmb, D[1][2 * bfp + 1], 0, 0, 0);
                }
                float part[4];
#pragma unroll
                for (int bf = 0; bf < 4; ++bf) {
                    float p_ = 0.f;
#pragma unroll
                    for (int pf = 0; pf < 2; ++pf)
#pragma unroll
                        for (int r = 0; r < 4; ++r) p_ += sreg[bf][pf * 4 + r] * D[pf][bf][r];
                    p_ += __shfl_xor(p_, 16);
                    p_ += __shfl_xor(p_, 32);
                    part[bf] = p_;
                }
                const int hb = l >> 4;
                const float wval = hb == 0 ? part[0] : hb == 1 ? part[1] : hb == 2 ? part[2] : part[3];
                L[ipl * 2 + half][j][(l & 15) + 16 * hb] = wval;
            }
            A0 = nA0; A1 = nA1;
        }
    }
    __syncthreads();

    {
        const int b = t & 63, ii = t >> 6;
        float lv[32];
        float m = -1e30f;
#pragma unroll
        for (int j = 0; j < 32; ++j) { lv[j] = L[ii][j][b]; m = fmaxf(m, lv[j]); }
        float s = 0.f;
#pragma unroll
        for (int j = 0; j < 32; ++j) { lv[j] = __expf(lv[j] - m); s += lv[j]; }
        const float inv = 1.f / s;
#pragma unroll
        for (int j = 0; j < 32; ++j) L[ii][j][b] = lv[j] * inv;
    }
    __syncthreads();

    {
        const int jw = t >> 4, r = t & 15;
#pragma unroll 1
        for (int ii = 0; ii < 8; ++ii) {
            h4 c4;
#pragma unroll
            for (int e = 0; e < 4; ++e) c4[e] = (_Float16)L[ii][jw][16 * e + r];
            *reinterpret_cast<h4*>(cp + ((size_t)jw * NI + i0 + ii) * 64 + r * 4) = c4;
        }
    }
}

// K2: ACC[b,j,p] += sum_i c[b,j,i]*hat[b,j,i,p]   (R15 verbatim)
// LDS-staged A stream (3 slots x 2 KB/wave, counted vmcnt) + two-round
// cross-wave reduce epilogue -> SMEM union 48 KB.
__global__ __launch_bounds__(512)
void accum_kernel(const h8* __restrict__ wp, const h8* __restrict__ xp,
                  const _Float16* __restrict__ cp, float* __restrict__ ACC)
{
    __shared__ char SMEM[49152];   // staging 48 KB | epilogue R[4][64*36] 36 KB
    const int t = threadIdx.x, wv = t >> 6, l = t & 63;
    const int j = blockIdx.x >> 4, is = blockIdx.x & 15;
    const int ioff = (l >= 32) ? 1 : 0;

    f4 D[2][4];
#pragma unroll
    for (int pf = 0; pf < 2; ++pf)
#pragma unroll
        for (int bf = 0; bf < 4; ++bf) { f4 Z = {0.f, 0.f, 0.f, 0.f}; D[pf][bf] = Z; }

    const int pbase = is * 64 + wv * 8;
    const h8* wj = wp + (size_t)j * NIP * 2 * 64 + l;   // lane-resolved ptr
    const _Float16* cj = cp + ((size_t)j * NI + ioff) * 64 + (l & 15) * 4;

    char* stg = SMEM + wv * 6144;   // 3 slots x 2048 B, wave-private

    auto STAGE = [&](int ipl) {
        const int slot = ipl % 3;
        const h8* src = wj + (size_t)(pbase + ipl) * 128;
        __builtin_amdgcn_global_load_lds(
            (const __attribute__((address_space(1))) void*)(src),
            (__attribute__((address_space(3))) void*)(stg + slot * 2048), 16, 0, 0);
        __builtin_amdgcn_global_load_lds(
            (const __attribute__((address_space(1))) void*)(src + 64),
            (__attribute__((address_space(3))) void*)(stg + slot * 2048 + 1024), 16, 0, 0);
    };

    STAGE(0);
    STAGE(1);

#pragma unroll 1
    for (int ipl = 0; ipl < 8; ++ipl) {
        const int ipg = pbase + ipl;
        if (ipl + 2 < 8) STAGE(ipl + 2);

        if (ipl < 6)       asm volatile("s_waitcnt vmcnt(4)" ::: "memory");
        else if (ipl == 6) asm volatile("s_waitcnt vmcnt(2)" ::: "memory");
        else               asm volatile("s_waitcnt vmcnt(0)" ::: "memory");
        __builtin_amdgcn_sched_barrier(0);

        const int slot = ipl % 3;
        const h8 A0 = *reinterpret_cast<const h8*>(stg + slot * 2048 + l * 16);
        const h8 A1 = *reinterpret_cast<const h8*>(stg + slot * 2048 + 1024 + l * 16);

        const h8* xpb = xp + (size_t)ipg * 4 * 64 + l;
        const h4 c4 = *reinterpret_cast<const h4*>(cj + (size_t)(2 * ipg) * 64);
        const h8 b0 = xpb[0] * c4[0];
        const h8 b1 = xpb[64] * c4[1];
        const h8 b2 = xpb[128] * c4[2];
        const h8 b3 = xpb[192] * c4[3];

        D[0][0] = __builtin_amdgcn_mfma_f32_16x16x32_f16(A0, b0, D[0][0], 0, 0, 0);
        D[1][0] = __builtin_amdgcn_mfma_f32_16x16x32_f16(A1, b0, D[1][0], 0, 0, 0);
        D[0][1] = __builtin_amdgcn_mfma_f32_16x16x32_f16(A0, b1, D[0][1], 0, 0, 0);
        D[1][1] = __builtin_amdgcn_mfma_f32_16x16x32_f16(A1, b1, D[1][1], 0, 0, 0);
        D[0][2] = __builtin_amdgcn_mfma_f32_16x16x32_f16(A0, b2, D[0][2], 0, 0, 0);
        D[1][2] = __builtin_amdgcn_mfma_f32_16x16x32_f16(A1, b2, D[1][2], 0, 0, 0);
        D[0][3] = __builtin_amdgcn_mfma_f32_16x16x32_f16(A0, b3, D[0][3], 0, 0, 0);
        D[1][3] = __builtin_amdgcn_mfma_f32_16x16x32_f16(A1, b3, D[1][3], 0, 0, 0);
    }

    // epilogue: two-round cross-wave reduce in R[4][64*36] (36 KB)
    __syncthreads();   // all staging consumed before SMEM reuse
    float (*R)[64 * 36] = reinterpret_cast<float (*)[64 * 36]>(SMEM);
    if (wv < 4) {
#pragma unroll
        for (int pf = 0; pf < 2; ++pf)
#pragma unroll
            for (int bf = 0; bf < 4; ++bf) {
                const int b = (l & 15) + 16 * bf, p = (l >> 4) * 4 + 16 * pf;
                *reinterpret_cast<f4*>(&R[wv][b * 36 + p]) = D[pf][bf];
            }
    }
    __syncthreads();
    if (wv >= 4) {
#pragma unroll
        for (int pf = 0; pf < 2; ++pf)
#pragma unroll
            for (int bf = 0; bf < 4; ++bf) {
                const int b = (l & 15) + 16 * bf, p = (l >> 4) * 4 + 16 * pf;
                f4* dst = reinterpret_cast<f4*>(&R[wv - 4][b * 36 + p]);
                *dst = *dst + D[pf][bf];
            }
    }
    __syncthreads();
#pragma unroll
    for (int k = 0; k < 4; ++k) {
        const int id = t + k * 512;
        const int b = id >> 5, p = id & 31;
        float s = 0.f;
#pragma unroll
        for (int w4 = 0; w4 < 4; ++w4) s += R[w4][b * 36 + p];
        atomicAdd(ACC + ((size_t)b * NJ + j) * NP + p, s);
    }
}

// OUT = squash(U*scale) (+ ADD) over last axis (P=32)
__global__ __launch_bounds__(256)
void squash_kernel(const float* __restrict__ U, const float* __restrict__ ADD,
                   float* __restrict__ OUT, float scale)
{
    const int t   = threadIdx.x;
    const int row = blockIdx.x * 8 + (t >> 5);
    const int p   = t & 31;
    const float val = U[row * 32 + p] * scale;
    float sq = val * val;
#pragma unroll
    for (int d = 1; d < 32; d <<= 1) sq += __shfl_xor(sq, d);
    float o = val * sqscale(sq);
    if (ADD != nullptr) o += ADD[row * 32 + p];
    OUT[row * 32 + p] = o;
}

extern "C" void kernel_launch(void* const* d_in, const int* in_sizes, int n_in,
                              void* d_out, int out_size, void* d_ws, size_t ws_size,
                              hipStream_t stream)
{
    const float* X  = (const float*)d_in[0];   // [64, 2048, 16]
    const float* Wg = (const float*)d_in[1];   // [32, 2048, 32, 16]
    float* out = (float*)d_out;                // [64, 32, 32]

    // ws: v1u,v2u,ou (768 KB, zeroed) | S2,S3 (512 KB) | xp 4 MB | cp 8 MB | wp 64 MB
    float* v1u = (float*)d_ws;
    float* v2u = v1u + VSZ;
    float* ou  = v2u + VSZ;
    float* S2  = ou  + VSZ;
    float* S3  = S2  + VSZ;
    h8* xp = (h8*)((char*)d_ws + (size_t)5 * VSZ * 4);
    _Float16* cp = (_Float16*)((char*)xp + (size_t)NIP * 4 * 64 * 16);
    h8* wpk = (h8*)((char*)cp + (size_t)NJ * NI * 64 * 2);

    // xpack + zero sweep in one launch (8 launches total)
    xpack_kernel<<<NIP + ZBLK, 256, 0, stream>>>(X, xp, (f4*)d_ws);

    // pass A fused with W packing: wp + v1u
    wacc_kernel<<<512, 512, 0, stream>>>(Wg, xp, wpk, v1u);

    // iter 2: S2 = squash(v1u/32); logits -> cp; weighted accum -> v2u
    squash_kernel<<<VSZ / 256, 256, 0, stream>>>(v1u, nullptr, S2, 1.f / 32.f);
    logits_kernel<<<NI / 8, 512, 0, stream>>>(wpk, xp, S2, cp);
    accum_kernel<<<512, 512, 0, stream>>>(wpk, xp, cp, v2u);

    // iter 3: S3 = squash(v2u) + S2; logits -> cp; accum -> ou
    squash_kernel<<<VSZ / 256, 256, 0, stream>>>(v2u, S2, S3, 1.f);
    logits_kernel<<<NI / 8, 512, 0, stream>>>(wpk, xp, S3, cp);
    accum_kernel<<<512, 512, 0, stream>>>(wpk, xp, cp, ou);

    squash_kernel<<<VSZ / 256, 256, 0, stream>>>(ou, nullptr, out, 1.f);
}